// Round 10
// baseline (1472.736 us; speedup 1.0000x reference)
//
#include <hip/hip_runtime.h>
#include <math.h>

// GATv2 x2 layers, N=50000, E=600000, D=128.
//  CSR over dst (zero(in pre)+count+scan1+scan3(fused)+scatter) ->
//  per layer: register-resident-W MFMA GEMM (XL/XR/RES all bf16),
//  then per-node aggregation: persistent waves (atomic work stealing),
//  two contiguous 32-lane halves/node, 4 dims/lane uint2 gathers, 4-edge
//  unroll with next-batch index prefetch, native-f32x2 math, no-max softmax
//  via exp2 (validated r6-r9).

#define DIM 128
#define NEG_SLOPE 0.2f
#define TPW 4

typedef __attribute__((ext_vector_type(8))) short short8;
typedef __attribute__((ext_vector_type(4))) float floatx4;
typedef __attribute__((ext_vector_type(2))) float f32x2;

static __device__ __forceinline__ unsigned short f2b(float f) {
    unsigned u = __float_as_uint(f);
    unsigned r = (u + 0x7FFFu + ((u >> 16) & 1u)) >> 16;   // RNE
    return (unsigned short)r;
}
// one u32 holding two bf16 (lo = dim d, hi = dim d+1) -> f32 pair
static __device__ __forceinline__ f32x2 cvt2(unsigned u) {
    f32x2 r;
    r.x = __uint_as_float(u << 16);
    r.y = __uint_as_float(u & 0xffff0000u);
    return r;
}
static __device__ __forceinline__ f32x2 abs2(f32x2 a) {
    f32x2 r;
    r.x = __builtin_fabsf(a.x);
    r.y = __builtin_fabsf(a.y);
    return r;
}

// ---------------- CSR build ----------------
__global__ void k_count(const int* __restrict__ dst, int E, int* __restrict__ counts) {
    int k = blockIdx.x * blockDim.x + threadIdx.x;
    if (k < E) atomicAdd(&counts[dst[k]], 1);
}

__global__ void k_scan1(const int* __restrict__ counts, int n,
                        int* __restrict__ rowptr, int* __restrict__ bsum) {
    __shared__ int s[256];
    int tid = threadIdx.x;
    int i = blockIdx.x * 256 + tid;
    int v = (i < n) ? (counts[i] + 1) : 0;   // +1 self loop
    s[tid] = v;
    __syncthreads();
    for (int off = 1; off < 256; off <<= 1) {
        int t = (tid >= off) ? s[tid - off] : 0;
        __syncthreads();
        s[tid] += t;
        __syncthreads();
    }
    if (i < n) rowptr[i + 1] = s[tid];
    if (tid == 255) bsum[blockIdx.x] = s[255];
}

// fused: scan bsum in-block (nb<=256), add offsets, emit cursors
__global__ void k_scan3(int* __restrict__ rowptr, const int* __restrict__ bsum,
                        int n, int* __restrict__ counts_to_cursors, int nb) {
    __shared__ int s[256];
    int tid = threadIdx.x;
    int v = (tid < nb) ? bsum[tid] : 0;
    s[tid] = v;
    __syncthreads();
    for (int off = 1; off < 256; off <<= 1) {
        int t = (tid >= off) ? s[tid - off] : 0;
        __syncthreads();
        s[tid] += t;
        __syncthreads();
    }
    int add = (blockIdx.x > 0) ? s[blockIdx.x - 1] : 0;
    int i = blockIdx.x * 256 + tid;
    if (i < n) {
        int cnt = counts_to_cursors[i] + 1;
        int vv = rowptr[i + 1] + add;
        rowptr[i + 1] = vv;
        counts_to_cursors[i] = vv - cnt;  // cursor = exclusive prefix
    }
    if (i == 0) rowptr[0] = 0;
}

__global__ void k_scatter(const int* __restrict__ src, const int* __restrict__ dst,
                          int E, int n, int* __restrict__ cur, int* __restrict__ srt) {
    int k = blockIdx.x * blockDim.x + threadIdx.x;
    int tot = E + n;
    if (k >= tot) return;
    int s, d;
    if (k < E) { s = src[k]; d = dst[k]; }
    else       { s = k - E;  d = s; }
    int p = atomicAdd(&cur[d], 1);
    srt[p] = s;
}

// ---------------- fused pre-pass: W frag + H frag + zero(tmpc+counters) ----------------
__global__ void k_pre(const float* __restrict__ Wl, const float* __restrict__ Wr,
                      const float* __restrict__ Wres, unsigned short* __restrict__ wfrag,
                      const float* __restrict__ h, unsigned short* __restrict__ hfrag,
                      int* __restrict__ tmpc, int n, int ntiles) {
    int blk = blockIdx.x;
    if (blk < 48) {
        int idx = blk * 256 + threadIdx.x;      // < 2*3*4*8*64 = 12288
        int lane = idx & 63;
        int nr   = (idx >> 6) & 7;
        int ks   = (idx >> 9) & 3;
        int v    = idx >> 11;                   // l*3+sec
        int sec = v % 3, l = v / 3;
        const float* W = (sec == 0) ? (Wl + l * DIM * DIM)
                       : (sec == 1) ? (Wr + l * DIM * DIM) : Wres;
        int nn = nr * 16 + (lane & 15);
        int k0 = ks * 32 + ((lane >> 4) << 3);
        ushort4 a, b;
        a.x = f2b(W[(k0 + 0) * DIM + nn]); a.y = f2b(W[(k0 + 1) * DIM + nn]);
        a.z = f2b(W[(k0 + 2) * DIM + nn]); a.w = f2b(W[(k0 + 3) * DIM + nn]);
        b.x = f2b(W[(k0 + 4) * DIM + nn]); b.y = f2b(W[(k0 + 5) * DIM + nn]);
        b.z = f2b(W[(k0 + 6) * DIM + nn]); b.w = f2b(W[(k0 + 7) * DIM + nn]);
        *(ushort4*)(wfrag + (size_t)idx * 8) = a;
        *(ushort4*)(wfrag + (size_t)idx * 8 + 4) = b;
    } else if (blk < 48 + ntiles) {
        int idx = (blk - 48) * 256 + threadIdx.x;
        int lane = idx & 63;
        int ks   = (idx >> 6) & 3;
        int tile = idx >> 8;
        int row  = tile * 16 + (lane & 15);
        int col0 = ks * 32 + ((lane >> 4) << 3);
        ushort4 a = {0, 0, 0, 0}, b = {0, 0, 0, 0};
        if (row < n) {
            float4 v0 = *(const float4*)(h + (size_t)row * DIM + col0);
            float4 v1 = *(const float4*)(h + (size_t)row * DIM + col0 + 4);
            a.x = f2b(v0.x); a.y = f2b(v0.y); a.z = f2b(v0.z); a.w = f2b(v0.w);
            b.x = f2b(v1.x); b.y = f2b(v1.y); b.z = f2b(v1.z); b.w = f2b(v1.w);
        }
        *(ushort4*)(hfrag + (size_t)idx * 8) = a;
        *(ushort4*)(hfrag + (size_t)idx * 8 + 4) = b;
    } else {
        int i = (blk - 48 - ntiles) * 256 + threadIdx.x;
        if (i < n + 4) tmpc[i] = 0;    // counts + 4 counter slots
    }
}

// ---------------- register-resident-W MFMA GEMM (all outputs bf16) ----------------
__global__ __launch_bounds__(256, 2) void k_gemm(
    const unsigned short* __restrict__ hfrag, const unsigned short* __restrict__ wfrag,
    const float* __restrict__ bl, const float* __restrict__ br, const float* __restrict__ bres,
    unsigned short* __restrict__ XLb, unsigned short* __restrict__ XRb,
    unsigned short* __restrict__ RESb, int ntiles)
{
    int sec  = blockIdx.y;
    int lane = threadIdx.x & 63;
    int w    = threadIdx.x >> 6;

    const unsigned short* wbase = wfrag + (size_t)sec * (4 * 8 * 64 * 8);
    short8 bf[4][8];
#pragma unroll
    for (int ks = 0; ks < 4; ks++)
#pragma unroll
        for (int nr = 0; nr < 8; nr++)
            bf[ks][nr] = *(const short8*)(wbase + (((ks * 8 + nr) * 64 + lane) << 3));

    const float* bias = (sec == 0) ? bl : (sec == 1) ? br : bres;
    unsigned short* C = (sec == 0) ? XLb : (sec == 1) ? XRb : RESb;
    int colb = (lane >> 4) << 2;
    float4 bv[8];
#pragma unroll
    for (int nr = 0; nr < 8; nr++) bv[nr] = *(const float4*)(bias + nr * 16 + colb);

    int wid = blockIdx.x * 4 + w;
#pragma unroll
    for (int i = 0; i < TPW; i++) {
        int t = wid * TPW + i;
        if (t >= ntiles) break;
        short8 a[4];
#pragma unroll
        for (int ks = 0; ks < 4; ks++)
            a[ks] = *(const short8*)(hfrag + (((t * 4 + ks) * 64 + lane) << 3));
        floatx4 acc[8];
#pragma unroll
        for (int nr = 0; nr < 8; nr++) acc[nr] = (floatx4){0.f, 0.f, 0.f, 0.f};
#pragma unroll
        for (int ks = 0; ks < 4; ks++)
#pragma unroll
            for (int nr = 0; nr < 8; nr++)
                acc[nr] = __builtin_amdgcn_mfma_f32_16x16x32_bf16(bf[ks][nr], a[ks], acc[nr], 0, 0, 0);

        int row = t * 16 + (lane & 15);
        size_t rb = (size_t)row * DIM;
#pragma unroll
        for (int nr = 0; nr < 8; nr++) {
            ushort4 u;
            u.x = f2b(acc[nr][0] + bv[nr].x);
            u.y = f2b(acc[nr][1] + bv[nr].y);
            u.z = f2b(acc[nr][2] + bv[nr].z);
            u.w = f2b(acc[nr][3] + bv[nr].w);
            *(ushort4*)(C + rb + nr * 16 + colb) = u;
        }
    }
}

// ---------------- aggregation ----------------
// Persistent waves: each wave atomically grabs node ids. Per node: two
// contiguous 32-lane halves, 4 dims/lane (uint2), 4-edge unroll with
// next-batch index prefetch, no-max softmax via exp2 (att log2e-folded).
#define EDGE_P(K)                                                        \
    f32x2 v01_##K = cvt2(e##K.x), v23_##K = cvt2(e##K.y);                \
    float p##K;                                                          \
    {                                                                    \
        f32x2 t01 = v01_##K + x01;                                       \
        f32x2 t23 = v23_##K + x23;                                       \
        f32x2 pp = a6_01 * t01 + a4_01 * abs2(t01);                      \
        pp += a6_23 * t23;                                               \
        pp += a4_23 * abs2(t23);                                         \
        p##K = pp.x + pp.y;                                              \
    }

__global__ __launch_bounds__(256, 8) void k_aggr(
    const unsigned short* __restrict__ XLb, const unsigned short* __restrict__ XRb,
    const unsigned short* __restrict__ RESb, const float* __restrict__ att,
    const float* __restrict__ bias, const int* __restrict__ rowptr,
    const int* __restrict__ srt, float* __restrict__ outF,
    unsigned short* __restrict__ fragOut, int* __restrict__ workCnt,
    int writeFrag, int n)
{
    int lane = threadIdx.x & 63;
    int half = lane >> 5, sl = lane & 31;
    int d0 = sl << 2;

    const float S6 = 0.6f * 1.44269504089f;   // log2(e) folded
    const float S4 = 0.4f * 1.44269504089f;
    float4 af = *(const float4*)(att + d0);
    f32x2 a6_01 = {S6 * af.x, S6 * af.y}, a6_23 = {S6 * af.z, S6 * af.w};
    f32x2 a4_01 = {S4 * af.x, S4 * af.y}, a4_23 = {S4 * af.z, S4 * af.w};
    float4 b4 = *(const float4*)(bias + d0);

    const uint2* R = (const uint2*)XLb;   // row i slice at R[i*32 + sl]

    for (;;) {
        int node;
        if (lane == 0) node = atomicAdd(workCnt, 1);
        node = __shfl(node, 0);
        if (node >= n) break;

        uint2 xru = *(const uint2*)(XRb + (size_t)node * DIM + d0);
        f32x2 x01 = cvt2(xru.x), x23 = cvt2(xru.y);

        int beg = rowptr[node], end = rowptr[node + 1];
        int len = end - beg;
        int hl = (len + 1) >> 1;
        int sb = beg + half * hl;
        int se = half ? end : (beg + hl);

        f32x2 acc01 = {0.f, 0.f}, acc23 = {0.f, 0.f};
        float den = 0.f;

        if (sb < se) {
            // preload first index batch
            int i0 = srt[sb];
            int i1 = srt[(sb + 1 < se) ? sb + 1 : se - 1];
            int i2 = srt[(sb + 2 < se) ? sb + 2 : se - 1];
            int i3 = srt[(sb + 3 < se) ? sb + 3 : se - 1];
            for (int j = sb; j < se; j += 4) {
                uint2 e0 = R[(size_t)i0 * 32 + sl];
                uint2 e1 = R[(size_t)i1 * 32 + sl];
                uint2 e2 = R[(size_t)i2 * 32 + sl];
                uint2 e3 = R[(size_t)i3 * 32 + sl];
                int jn = j + 4;
                if (jn < se) {      // prefetch next batch indices during math
                    i0 = srt[jn];
                    i1 = srt[(jn + 1 < se) ? jn + 1 : se - 1];
                    i2 = srt[(jn + 2 < se) ? jn + 2 : se - 1];
                    i3 = srt[(jn + 3 < se) ? jn + 3 : se - 1];
                }
                EDGE_P(0) EDGE_P(1) EDGE_P(2) EDGE_P(3)
#pragma unroll
                for (int off = 16; off >= 1; off >>= 1) {
                    p0 += __shfl_xor(p0, off);
                    p1 += __shfl_xor(p1, off);
                    p2 += __shfl_xor(p2, off);
                    p3 += __shfl_xor(p3, off);
                }
                float w0 = __builtin_exp2f(fminf(p0, 120.f));
                float w1 = (j + 1 < se) ? __builtin_exp2f(fminf(p1, 120.f)) : 0.f;
                float w2 = (j + 2 < se) ? __builtin_exp2f(fminf(p2, 120.f)) : 0.f;
                float w3 = (j + 3 < se) ? __builtin_exp2f(fminf(p3, 120.f)) : 0.f;
                den += (w0 + w1) + (w2 + w3);
                acc01 += w0 * v01_0 + w1 * v01_1;
                acc23 += w0 * v23_0 + w1 * v23_1;
                acc01 += w2 * v01_2 + w3 * v01_3;
                acc23 += w2 * v23_2 + w3 * v23_3;
            }
        }

        // merge the two halves (pure sums)
        den     += __shfl_xor(den, 32);
        acc01.x += __shfl_xor(acc01.x, 32);
        acc01.y += __shfl_xor(acc01.y, 32);
        acc23.x += __shfl_xor(acc23.x, 32);
        acc23.y += __shfl_xor(acc23.y, 32);
        if (half) continue;

        float inv = 1.f / (den + 1e-16f);
        uint2 ru = *(const uint2*)(RESb + (size_t)node * DIM + d0);
        f32x2 r01 = cvt2(ru.x), r23 = cvt2(ru.y);
        float4 o;
        o.x = fmaxf(acc01.x * inv + b4.x + r01.x, 0.f);
        o.y = fmaxf(acc01.y * inv + b4.y + r01.y, 0.f);
        o.z = fmaxf(acc23.x * inv + b4.z + r23.x, 0.f);
        o.w = fmaxf(acc23.y * inv + b4.w + r23.y, 0.f);

        if (writeFrag) {
            int tile = node >> 4;
            int ks = sl >> 3;
            int li = (node & 15) + (((sl >> 1) & 3) << 4);
            int j0 = (sl & 1) << 2;
            ushort4 u;
            u.x = f2b(o.x); u.y = f2b(o.y); u.z = f2b(o.z); u.w = f2b(o.w);
            *(ushort4*)(fragOut + ((size_t)((tile * 4 + ks) * 64 + li) << 3) + j0) = u;
        } else {
            *(float4*)(outF + (size_t)node * DIM + d0) = o;
        }
    }
}

extern "C" void kernel_launch(void* const* d_in, const int* in_sizes, int n_in,
                              void* d_out, int out_size, void* d_ws, size_t ws_size,
                              hipStream_t stream) {
    const float* x    = (const float*)d_in[0];
    const int*   ei   = (const int*)d_in[1];
    const float* Wl   = (const float*)d_in[2];
    const float* bl   = (const float*)d_in[3];
    const float* Wr   = (const float*)d_in[4];
    const float* br   = (const float*)d_in[5];
    const float* att  = (const float*)d_in[6];
    const float* bias = (const float*)d_in[7];
    const float* Wres = (const float*)d_in[8];
    const float* bres = (const float*)d_in[9];

    int n = in_sizes[0] / DIM;
    int E = in_sizes[1] / 2;
    int ntiles = (n + 15) >> 4;
    const int* srcIdx = ei;
    const int* dstIdx = ei + E;

    // workspace layout
    unsigned short* xlb   = (unsigned short*)d_ws;
    unsigned short* xrb   = xlb + (size_t)n * DIM;
    unsigned short* resb  = xrb + (size_t)n * DIM;
    unsigned short* hfrag = resb + (size_t)n * DIM;
    unsigned short* wfrag = hfrag + (size_t)ntiles * 16 * DIM;
    int* rowptr = (int*)(wfrag + 2 * 3 * DIM * DIM);
    int* tmpc   = rowptr + (n + 1);
    int* cnts   = tmpc + n;                 // 4 counter slots (zeroed in k_pre)
    int* srt    = cnts + 4;                 // E+n used, +8 pad
    int* bsum   = srt + (E + n + 8);

    int nb1 = (n + 255) / 256;   // 196 <= 256
    int nbz = (n + 4 + 255) / 256;

    k_pre<<<48 + ntiles + nbz, 256, 0, stream>>>(Wl, Wr, Wres, wfrag, x, hfrag,
                                                 tmpc, n, ntiles);
    k_count<<<(E + 255) / 256, 256, 0, stream>>>(dstIdx, E, tmpc);
    k_scan1<<<nb1, 256, 0, stream>>>(tmpc, n, rowptr, bsum);
    k_scan3<<<nb1, 256, 0, stream>>>(rowptr, bsum, n, tmpc, nb1);
    k_scatter<<<(E + n + 255) / 256, 256, 0, stream>>>(srcIdx, dstIdx, E, n, tmpc, srt);

    int gx = (ntiles + 4 * TPW - 1) / (4 * TPW);
    for (int l = 0; l < 2; l++) {
        dim3 g(gx, 3);
        k_gemm<<<g, 256, 0, stream>>>(hfrag, wfrag + (size_t)l * 3 * 4 * 8 * 64 * 8,
                                      bl + (size_t)l * DIM, br + (size_t)l * DIM, bres,
                                      xlb, xrb, resb, ntiles);
        k_aggr<<<2048, 256, 0, stream>>>(xlb, xrb, resb, att + (size_t)l * DIM,
                                         bias + (size_t)l * DIM, rowptr, srt,
                                         (float*)d_out, hfrag, cnts + l,
                                         (l == 0) ? 1 : 0, n);
    }
}

// Round 11
// 206.998 us; speedup vs baseline: 7.1147x; 7.1147x over previous
//
#include <hip/hip_runtime.h>
#include <math.h>

// GATv2 x2 layers, N=50000, E=600000, D=128.
//  CSR over dst (zero(in pre)+count+scan1+scan3(fused)+scatter) ->
//  per layer: register-resident-W MFMA GEMM (XL/XR/RES all bf16),
//  then per-node aggregation: static 4 nodes/block (NO work stealing --
//  r10 showed a single atomic counter costs 13-600x), two contiguous
//  32-lane halves/node, 4 dims/lane uint2 gathers, 4-edge unroll,
//  native-f32x2 math, no-max softmax via exp2 (validated r6-r10).

#define DIM 128
#define NEG_SLOPE 0.2f
#define TPW 4

typedef __attribute__((ext_vector_type(8))) short short8;
typedef __attribute__((ext_vector_type(4))) float floatx4;
typedef __attribute__((ext_vector_type(2))) float f32x2;

static __device__ __forceinline__ unsigned short f2b(float f) {
    unsigned u = __float_as_uint(f);
    unsigned r = (u + 0x7FFFu + ((u >> 16) & 1u)) >> 16;   // RNE
    return (unsigned short)r;
}
// one u32 holding two bf16 (lo = dim d, hi = dim d+1) -> f32 pair
static __device__ __forceinline__ f32x2 cvt2(unsigned u) {
    f32x2 r;
    r.x = __uint_as_float(u << 16);
    r.y = __uint_as_float(u & 0xffff0000u);
    return r;
}
static __device__ __forceinline__ f32x2 abs2(f32x2 a) {
    f32x2 r;
    r.x = __builtin_fabsf(a.x);
    r.y = __builtin_fabsf(a.y);
    return r;
}

// ---------------- CSR build ----------------
__global__ void k_count(const int* __restrict__ dst, int E, int* __restrict__ counts) {
    int k = blockIdx.x * blockDim.x + threadIdx.x;
    if (k < E) atomicAdd(&counts[dst[k]], 1);
}

__global__ void k_scan1(const int* __restrict__ counts, int n,
                        int* __restrict__ rowptr, int* __restrict__ bsum) {
    __shared__ int s[256];
    int tid = threadIdx.x;
    int i = blockIdx.x * 256 + tid;
    int v = (i < n) ? (counts[i] + 1) : 0;   // +1 self loop
    s[tid] = v;
    __syncthreads();
    for (int off = 1; off < 256; off <<= 1) {
        int t = (tid >= off) ? s[tid - off] : 0;
        __syncthreads();
        s[tid] += t;
        __syncthreads();
    }
    if (i < n) rowptr[i + 1] = s[tid];
    if (tid == 255) bsum[blockIdx.x] = s[255];
}

// fused: scan bsum in-block (nb<=256), add offsets, emit cursors
__global__ void k_scan3(int* __restrict__ rowptr, const int* __restrict__ bsum,
                        int n, int* __restrict__ counts_to_cursors, int nb) {
    __shared__ int s[256];
    int tid = threadIdx.x;
    int v = (tid < nb) ? bsum[tid] : 0;
    s[tid] = v;
    __syncthreads();
    for (int off = 1; off < 256; off <<= 1) {
        int t = (tid >= off) ? s[tid - off] : 0;
        __syncthreads();
        s[tid] += t;
        __syncthreads();
    }
    int add = (blockIdx.x > 0) ? s[blockIdx.x - 1] : 0;
    int i = blockIdx.x * 256 + tid;
    if (i < n) {
        int cnt = counts_to_cursors[i] + 1;
        int vv = rowptr[i + 1] + add;
        rowptr[i + 1] = vv;
        counts_to_cursors[i] = vv - cnt;  // cursor = exclusive prefix
    }
    if (i == 0) rowptr[0] = 0;
}

__global__ void k_scatter(const int* __restrict__ src, const int* __restrict__ dst,
                          int E, int n, int* __restrict__ cur, int* __restrict__ srt) {
    int k = blockIdx.x * blockDim.x + threadIdx.x;
    int tot = E + n;
    if (k >= tot) return;
    int s, d;
    if (k < E) { s = src[k]; d = dst[k]; }
    else       { s = k - E;  d = s; }
    int p = atomicAdd(&cur[d], 1);
    srt[p] = s;
}

// ---------------- fused pre-pass: W frag + H frag + tmpc zero ----------------
__global__ void k_pre(const float* __restrict__ Wl, const float* __restrict__ Wr,
                      const float* __restrict__ Wres, unsigned short* __restrict__ wfrag,
                      const float* __restrict__ h, unsigned short* __restrict__ hfrag,
                      int* __restrict__ tmpc, int n, int ntiles) {
    int blk = blockIdx.x;
    if (blk < 48) {
        int idx = blk * 256 + threadIdx.x;      // < 2*3*4*8*64 = 12288
        int lane = idx & 63;
        int nr   = (idx >> 6) & 7;
        int ks   = (idx >> 9) & 3;
        int v    = idx >> 11;                   // l*3+sec
        int sec = v % 3, l = v / 3;
        const float* W = (sec == 0) ? (Wl + l * DIM * DIM)
                       : (sec == 1) ? (Wr + l * DIM * DIM) : Wres;
        int nn = nr * 16 + (lane & 15);
        int k0 = ks * 32 + ((lane >> 4) << 3);
        ushort4 a, b;
        a.x = f2b(W[(k0 + 0) * DIM + nn]); a.y = f2b(W[(k0 + 1) * DIM + nn]);
        a.z = f2b(W[(k0 + 2) * DIM + nn]); a.w = f2b(W[(k0 + 3) * DIM + nn]);
        b.x = f2b(W[(k0 + 4) * DIM + nn]); b.y = f2b(W[(k0 + 5) * DIM + nn]);
        b.z = f2b(W[(k0 + 6) * DIM + nn]); b.w = f2b(W[(k0 + 7) * DIM + nn]);
        *(ushort4*)(wfrag + (size_t)idx * 8) = a;
        *(ushort4*)(wfrag + (size_t)idx * 8 + 4) = b;
    } else if (blk < 48 + ntiles) {
        int idx = (blk - 48) * 256 + threadIdx.x;
        int lane = idx & 63;
        int ks   = (idx >> 6) & 3;
        int tile = idx >> 8;
        int row  = tile * 16 + (lane & 15);
        int col0 = ks * 32 + ((lane >> 4) << 3);
        ushort4 a = {0, 0, 0, 0}, b = {0, 0, 0, 0};
        if (row < n) {
            float4 v0 = *(const float4*)(h + (size_t)row * DIM + col0);
            float4 v1 = *(const float4*)(h + (size_t)row * DIM + col0 + 4);
            a.x = f2b(v0.x); a.y = f2b(v0.y); a.z = f2b(v0.z); a.w = f2b(v0.w);
            b.x = f2b(v1.x); b.y = f2b(v1.y); b.z = f2b(v1.z); b.w = f2b(v1.w);
        }
        *(ushort4*)(hfrag + (size_t)idx * 8) = a;
        *(ushort4*)(hfrag + (size_t)idx * 8 + 4) = b;
    } else {
        int i = (blk - 48 - ntiles) * 256 + threadIdx.x;
        if (i < n) tmpc[i] = 0;
    }
}

// ---------------- register-resident-W MFMA GEMM (all outputs bf16) ----------------
__global__ __launch_bounds__(256, 2) void k_gemm(
    const unsigned short* __restrict__ hfrag, const unsigned short* __restrict__ wfrag,
    const float* __restrict__ bl, const float* __restrict__ br, const float* __restrict__ bres,
    unsigned short* __restrict__ XLb, unsigned short* __restrict__ XRb,
    unsigned short* __restrict__ RESb, int ntiles)
{
    int sec  = blockIdx.y;
    int lane = threadIdx.x & 63;
    int w    = threadIdx.x >> 6;

    const unsigned short* wbase = wfrag + (size_t)sec * (4 * 8 * 64 * 8);
    short8 bf[4][8];
#pragma unroll
    for (int ks = 0; ks < 4; ks++)
#pragma unroll
        for (int nr = 0; nr < 8; nr++)
            bf[ks][nr] = *(const short8*)(wbase + (((ks * 8 + nr) * 64 + lane) << 3));

    const float* bias = (sec == 0) ? bl : (sec == 1) ? br : bres;
    unsigned short* C = (sec == 0) ? XLb : (sec == 1) ? XRb : RESb;
    int colb = (lane >> 4) << 2;
    float4 bv[8];
#pragma unroll
    for (int nr = 0; nr < 8; nr++) bv[nr] = *(const float4*)(bias + nr * 16 + colb);

    int wid = blockIdx.x * 4 + w;
#pragma unroll
    for (int i = 0; i < TPW; i++) {
        int t = wid * TPW + i;
        if (t >= ntiles) break;
        short8 a[4];
#pragma unroll
        for (int ks = 0; ks < 4; ks++)
            a[ks] = *(const short8*)(hfrag + (((t * 4 + ks) * 64 + lane) << 3));
        floatx4 acc[8];
#pragma unroll
        for (int nr = 0; nr < 8; nr++) acc[nr] = (floatx4){0.f, 0.f, 0.f, 0.f};
#pragma unroll
        for (int ks = 0; ks < 4; ks++)
#pragma unroll
            for (int nr = 0; nr < 8; nr++)
                acc[nr] = __builtin_amdgcn_mfma_f32_16x16x32_bf16(bf[ks][nr], a[ks], acc[nr], 0, 0, 0);

        int row = t * 16 + (lane & 15);
        size_t rb = (size_t)row * DIM;
#pragma unroll
        for (int nr = 0; nr < 8; nr++) {
            ushort4 u;
            u.x = f2b(acc[nr][0] + bv[nr].x);
            u.y = f2b(acc[nr][1] + bv[nr].y);
            u.z = f2b(acc[nr][2] + bv[nr].z);
            u.w = f2b(acc[nr][3] + bv[nr].w);
            *(ushort4*)(C + rb + nr * 16 + colb) = u;
        }
    }
}

// ---------------- aggregation ----------------
// Static 4 nodes/block. 1 wave/node, two contiguous 32-lane halves,
// 4 dims/lane (uint2), 4-edge unroll, native f32x2 math, no-max softmax
// via exp2 (att has log2e folded).
#define EDGE_P(K)                                                        \
    f32x2 v01_##K = cvt2(e##K.x), v23_##K = cvt2(e##K.y);                \
    float p##K;                                                          \
    {                                                                    \
        f32x2 t01 = v01_##K + x01;                                       \
        f32x2 t23 = v23_##K + x23;                                       \
        f32x2 pp = a6_01 * t01 + a4_01 * abs2(t01);                      \
        pp += a6_23 * t23;                                               \
        pp += a4_23 * abs2(t23);                                         \
        p##K = pp.x + pp.y;                                              \
    }

__global__ __launch_bounds__(256, 8) void k_aggr(
    const unsigned short* __restrict__ XLb, const unsigned short* __restrict__ XRb,
    const unsigned short* __restrict__ RESb, const float* __restrict__ att,
    const float* __restrict__ bias, const int* __restrict__ rowptr,
    const int* __restrict__ srt, float* __restrict__ outF,
    unsigned short* __restrict__ fragOut, int writeFrag, int n)
{
    int wave = threadIdx.x >> 6;
    int lane = threadIdx.x & 63;
    int node = blockIdx.x * 4 + wave;
    if (node >= n) return;
    int half = lane >> 5, sl = lane & 31;
    int d0 = sl << 2;

    const float S6 = 0.6f * 1.44269504089f;   // log2(e) folded
    const float S4 = 0.4f * 1.44269504089f;
    float4 af = *(const float4*)(att + d0);
    f32x2 a6_01 = {S6 * af.x, S6 * af.y}, a6_23 = {S6 * af.z, S6 * af.w};
    f32x2 a4_01 = {S4 * af.x, S4 * af.y}, a4_23 = {S4 * af.z, S4 * af.w};

    uint2 xru = *(const uint2*)(XRb + (size_t)node * DIM + d0);
    f32x2 x01 = cvt2(xru.x), x23 = cvt2(xru.y);

    int beg = rowptr[node], end = rowptr[node + 1];
    int len = end - beg;
    int hl = (len + 1) >> 1;
    int sb = beg + half * hl;
    int se = half ? end : (beg + hl);

    const uint2* R = (const uint2*)XLb;   // row i slice at R[i*32 + sl]

    f32x2 acc01 = {0.f, 0.f}, acc23 = {0.f, 0.f};
    float den = 0.f;

    for (int j = sb; j < se; j += 4) {
        int j1 = (j + 1 < se) ? j + 1 : j;
        int j2 = (j + 2 < se) ? j + 2 : j;
        int j3 = (j + 3 < se) ? j + 3 : j;
        int s0 = srt[j], s1 = srt[j1], s2 = srt[j2], s3 = srt[j3];
        uint2 e0 = R[(size_t)s0 * 32 + sl];
        uint2 e1 = R[(size_t)s1 * 32 + sl];
        uint2 e2 = R[(size_t)s2 * 32 + sl];
        uint2 e3 = R[(size_t)s3 * 32 + sl];
        EDGE_P(0) EDGE_P(1) EDGE_P(2) EDGE_P(3)
#pragma unroll
        for (int off = 16; off >= 1; off >>= 1) {
            p0 += __shfl_xor(p0, off);
            p1 += __shfl_xor(p1, off);
            p2 += __shfl_xor(p2, off);
            p3 += __shfl_xor(p3, off);
        }
        float w0 = __builtin_exp2f(fminf(p0, 120.f));
        float w1 = (j + 1 < se) ? __builtin_exp2f(fminf(p1, 120.f)) : 0.f;
        float w2 = (j + 2 < se) ? __builtin_exp2f(fminf(p2, 120.f)) : 0.f;
        float w3 = (j + 3 < se) ? __builtin_exp2f(fminf(p3, 120.f)) : 0.f;
        den += (w0 + w1) + (w2 + w3);
        acc01 += w0 * v01_0 + w1 * v01_1;
        acc23 += w0 * v23_0 + w1 * v23_1;
        acc01 += w2 * v01_2 + w3 * v01_3;
        acc23 += w2 * v23_2 + w3 * v23_3;
    }

    // merge the two halves (pure sums)
    den     += __shfl_xor(den, 32);
    acc01.x += __shfl_xor(acc01.x, 32);
    acc01.y += __shfl_xor(acc01.y, 32);
    acc23.x += __shfl_xor(acc23.x, 32);
    acc23.y += __shfl_xor(acc23.y, 32);
    if (half) return;

    float inv = 1.f / (den + 1e-16f);
    uint2 ru = *(const uint2*)(RESb + (size_t)node * DIM + d0);
    f32x2 r01 = cvt2(ru.x), r23 = cvt2(ru.y);
    float4 b4 = *(const float4*)(bias + d0);
    float4 o;
    o.x = fmaxf(acc01.x * inv + b4.x + r01.x, 0.f);
    o.y = fmaxf(acc01.y * inv + b4.y + r01.y, 0.f);
    o.z = fmaxf(acc23.x * inv + b4.z + r23.x, 0.f);
    o.w = fmaxf(acc23.y * inv + b4.w + r23.y, 0.f);

    if (writeFrag) {
        int tile = node >> 4;
        int ks = sl >> 3;
        int li = (node & 15) + (((sl >> 1) & 3) << 4);
        int j0 = (sl & 1) << 2;
        ushort4 u;
        u.x = f2b(o.x); u.y = f2b(o.y); u.z = f2b(o.z); u.w = f2b(o.w);
        *(ushort4*)(fragOut + ((size_t)((tile * 4 + ks) * 64 + li) << 3) + j0) = u;
    } else {
        *(float4*)(outF + (size_t)node * DIM + d0) = o;
    }
}

extern "C" void kernel_launch(void* const* d_in, const int* in_sizes, int n_in,
                              void* d_out, int out_size, void* d_ws, size_t ws_size,
                              hipStream_t stream) {
    const float* x    = (const float*)d_in[0];
    const int*   ei   = (const int*)d_in[1];
    const float* Wl   = (const float*)d_in[2];
    const float* bl   = (const float*)d_in[3];
    const float* Wr   = (const float*)d_in[4];
    const float* br   = (const float*)d_in[5];
    const float* att  = (const float*)d_in[6];
    const float* bias = (const float*)d_in[7];
    const float* Wres = (const float*)d_in[8];
    const float* bres = (const float*)d_in[9];

    int n = in_sizes[0] / DIM;
    int E = in_sizes[1] / 2;
    int ntiles = (n + 15) >> 4;
    const int* srcIdx = ei;
    const int* dstIdx = ei + E;

    // workspace layout
    unsigned short* xlb   = (unsigned short*)d_ws;
    unsigned short* xrb   = xlb + (size_t)n * DIM;
    unsigned short* resb  = xrb + (size_t)n * DIM;
    unsigned short* hfrag = resb + (size_t)n * DIM;
    unsigned short* wfrag = hfrag + (size_t)ntiles * 16 * DIM;
    int* rowptr = (int*)(wfrag + 2 * 3 * DIM * DIM);
    int* tmpc   = rowptr + (n + 1);
    int* srt    = tmpc + n;                 // E+n used, +8 pad
    int* bsum   = srt + (E + n + 8);

    int nb1 = (n + 255) / 256;   // 196 <= 256

    k_pre<<<48 + ntiles + nb1, 256, 0, stream>>>(Wl, Wr, Wres, wfrag, x, hfrag,
                                                 tmpc, n, ntiles);
    k_count<<<(E + 255) / 256, 256, 0, stream>>>(dstIdx, E, tmpc);
    k_scan1<<<nb1, 256, 0, stream>>>(tmpc, n, rowptr, bsum);
    k_scan3<<<nb1, 256, 0, stream>>>(rowptr, bsum, n, tmpc, nb1);
    k_scatter<<<(E + n + 255) / 256, 256, 0, stream>>>(srcIdx, dstIdx, E, n, tmpc, srt);

    int gx = (ntiles + 4 * TPW - 1) / (4 * TPW);
    for (int l = 0; l < 2; l++) {
        dim3 g(gx, 3);
        k_gemm<<<g, 256, 0, stream>>>(hfrag, wfrag + (size_t)l * 3 * 4 * 8 * 64 * 8,
                                      bl + (size_t)l * DIM, br + (size_t)l * DIM, bres,
                                      xlb, xrb, resb, ntiles);
        k_aggr<<<(n + 3) / 4, 256, 0, stream>>>(xlb, xrb, resb, att + (size_t)l * DIM,
                                                bias + (size_t)l * DIM, rowptr, srt,
                                                (float*)d_out, hfrag, (l == 0) ? 1 : 0, n);
    }
}

// Round 12
// 201.822 us; speedup vs baseline: 7.2972x; 1.0256x over previous
//
#include <hip/hip_runtime.h>
#include <math.h>

// GATv2 x2 layers, N=50000, E=600000, D=128.
//  CSR over dst (zero(in pre)+count+scan1+scan3(fused)+scatter) ->
//  per layer: register-resident-W MFMA GEMM (XL/XR/RES all bf16),
//  then per-node aggregation: 2 nodes/wave (one per 32-lane half, NO
//  cross-half merge), 4 dims/lane uint2 gathers, 4-edge unroll,
//  native-f32x2 math, no-max softmax via exp2 (validated r6-r11).

#define DIM 128
#define NEG_SLOPE 0.2f
#define TPW 4

typedef __attribute__((ext_vector_type(8))) short short8;
typedef __attribute__((ext_vector_type(4))) float floatx4;
typedef __attribute__((ext_vector_type(2))) float f32x2;

static __device__ __forceinline__ unsigned short f2b(float f) {
    unsigned u = __float_as_uint(f);
    unsigned r = (u + 0x7FFFu + ((u >> 16) & 1u)) >> 16;   // RNE
    return (unsigned short)r;
}
// one u32 holding two bf16 (lo = dim d, hi = dim d+1) -> f32 pair
static __device__ __forceinline__ f32x2 cvt2(unsigned u) {
    f32x2 r;
    r.x = __uint_as_float(u << 16);
    r.y = __uint_as_float(u & 0xffff0000u);
    return r;
}
static __device__ __forceinline__ f32x2 abs2(f32x2 a) {
    f32x2 r;
    r.x = __builtin_fabsf(a.x);
    r.y = __builtin_fabsf(a.y);
    return r;
}

// ---------------- CSR build ----------------
__global__ void k_count(const int* __restrict__ dst, int E, int* __restrict__ counts) {
    int k = blockIdx.x * blockDim.x + threadIdx.x;
    if (k < E) atomicAdd(&counts[dst[k]], 1);
}

__global__ void k_scan1(const int* __restrict__ counts, int n,
                        int* __restrict__ rowptr, int* __restrict__ bsum) {
    __shared__ int s[256];
    int tid = threadIdx.x;
    int i = blockIdx.x * 256 + tid;
    int v = (i < n) ? (counts[i] + 1) : 0;   // +1 self loop
    s[tid] = v;
    __syncthreads();
    for (int off = 1; off < 256; off <<= 1) {
        int t = (tid >= off) ? s[tid - off] : 0;
        __syncthreads();
        s[tid] += t;
        __syncthreads();
    }
    if (i < n) rowptr[i + 1] = s[tid];
    if (tid == 255) bsum[blockIdx.x] = s[255];
}

// fused: scan bsum in-block (nb<=256), add offsets, emit cursors
__global__ void k_scan3(int* __restrict__ rowptr, const int* __restrict__ bsum,
                        int n, int* __restrict__ counts_to_cursors, int nb) {
    __shared__ int s[256];
    int tid = threadIdx.x;
    int v = (tid < nb) ? bsum[tid] : 0;
    s[tid] = v;
    __syncthreads();
    for (int off = 1; off < 256; off <<= 1) {
        int t = (tid >= off) ? s[tid - off] : 0;
        __syncthreads();
        s[tid] += t;
        __syncthreads();
    }
    int add = (blockIdx.x > 0) ? s[blockIdx.x - 1] : 0;
    int i = blockIdx.x * 256 + tid;
    if (i < n) {
        int cnt = counts_to_cursors[i] + 1;
        int vv = rowptr[i + 1] + add;
        rowptr[i + 1] = vv;
        counts_to_cursors[i] = vv - cnt;  // cursor = exclusive prefix
    }
    if (i == 0) rowptr[0] = 0;
}

__global__ void k_scatter(const int* __restrict__ src, const int* __restrict__ dst,
                          int E, int n, int* __restrict__ cur, int* __restrict__ srt) {
    int k = blockIdx.x * blockDim.x + threadIdx.x;
    int tot = E + n;
    if (k >= tot) return;
    int s, d;
    if (k < E) { s = src[k]; d = dst[k]; }
    else       { s = k - E;  d = s; }
    int p = atomicAdd(&cur[d], 1);
    srt[p] = s;
}

// ---------------- fused pre-pass: W frag + H frag + tmpc zero ----------------
__global__ void k_pre(const float* __restrict__ Wl, const float* __restrict__ Wr,
                      const float* __restrict__ Wres, unsigned short* __restrict__ wfrag,
                      const float* __restrict__ h, unsigned short* __restrict__ hfrag,
                      int* __restrict__ tmpc, int n, int ntiles) {
    int blk = blockIdx.x;
    if (blk < 48) {
        int idx = blk * 256 + threadIdx.x;      // < 2*3*4*8*64 = 12288
        int lane = idx & 63;
        int nr   = (idx >> 6) & 7;
        int ks   = (idx >> 9) & 3;
        int v    = idx >> 11;                   // l*3+sec
        int sec = v % 3, l = v / 3;
        const float* W = (sec == 0) ? (Wl + l * DIM * DIM)
                       : (sec == 1) ? (Wr + l * DIM * DIM) : Wres;
        int nn = nr * 16 + (lane & 15);
        int k0 = ks * 32 + ((lane >> 4) << 3);
        ushort4 a, b;
        a.x = f2b(W[(k0 + 0) * DIM + nn]); a.y = f2b(W[(k0 + 1) * DIM + nn]);
        a.z = f2b(W[(k0 + 2) * DIM + nn]); a.w = f2b(W[(k0 + 3) * DIM + nn]);
        b.x = f2b(W[(k0 + 4) * DIM + nn]); b.y = f2b(W[(k0 + 5) * DIM + nn]);
        b.z = f2b(W[(k0 + 6) * DIM + nn]); b.w = f2b(W[(k0 + 7) * DIM + nn]);
        *(ushort4*)(wfrag + (size_t)idx * 8) = a;
        *(ushort4*)(wfrag + (size_t)idx * 8 + 4) = b;
    } else if (blk < 48 + ntiles) {
        int idx = (blk - 48) * 256 + threadIdx.x;
        int lane = idx & 63;
        int ks   = (idx >> 6) & 3;
        int tile = idx >> 8;
        int row  = tile * 16 + (lane & 15);
        int col0 = ks * 32 + ((lane >> 4) << 3);
        ushort4 a = {0, 0, 0, 0}, b = {0, 0, 0, 0};
        if (row < n) {
            float4 v0 = *(const float4*)(h + (size_t)row * DIM + col0);
            float4 v1 = *(const float4*)(h + (size_t)row * DIM + col0 + 4);
            a.x = f2b(v0.x); a.y = f2b(v0.y); a.z = f2b(v0.z); a.w = f2b(v0.w);
            b.x = f2b(v1.x); b.y = f2b(v1.y); b.z = f2b(v1.z); b.w = f2b(v1.w);
        }
        *(ushort4*)(hfrag + (size_t)idx * 8) = a;
        *(ushort4*)(hfrag + (size_t)idx * 8 + 4) = b;
    } else {
        int i = (blk - 48 - ntiles) * 256 + threadIdx.x;
        if (i < n) tmpc[i] = 0;
    }
}

// ---------------- register-resident-W MFMA GEMM (all outputs bf16) ----------------
__global__ __launch_bounds__(256, 2) void k_gemm(
    const unsigned short* __restrict__ hfrag, const unsigned short* __restrict__ wfrag,
    const float* __restrict__ bl, const float* __restrict__ br, const float* __restrict__ bres,
    unsigned short* __restrict__ XLb, unsigned short* __restrict__ XRb,
    unsigned short* __restrict__ RESb, int ntiles)
{
    int sec  = blockIdx.y;
    int lane = threadIdx.x & 63;
    int w    = threadIdx.x >> 6;

    const unsigned short* wbase = wfrag + (size_t)sec * (4 * 8 * 64 * 8);
    short8 bf[4][8];
#pragma unroll
    for (int ks = 0; ks < 4; ks++)
#pragma unroll
        for (int nr = 0; nr < 8; nr++)
            bf[ks][nr] = *(const short8*)(wbase + (((ks * 8 + nr) * 64 + lane) << 3));

    const float* bias = (sec == 0) ? bl : (sec == 1) ? br : bres;
    unsigned short* C = (sec == 0) ? XLb : (sec == 1) ? XRb : RESb;
    int colb = (lane >> 4) << 2;
    float4 bv[8];
#pragma unroll
    for (int nr = 0; nr < 8; nr++) bv[nr] = *(const float4*)(bias + nr * 16 + colb);

    int wid = blockIdx.x * 4 + w;
#pragma unroll
    for (int i = 0; i < TPW; i++) {
        int t = wid * TPW + i;
        if (t >= ntiles) break;
        short8 a[4];
#pragma unroll
        for (int ks = 0; ks < 4; ks++)
            a[ks] = *(const short8*)(hfrag + (((t * 4 + ks) * 64 + lane) << 3));
        floatx4 acc[8];
#pragma unroll
        for (int nr = 0; nr < 8; nr++) acc[nr] = (floatx4){0.f, 0.f, 0.f, 0.f};
#pragma unroll
        for (int ks = 0; ks < 4; ks++)
#pragma unroll
            for (int nr = 0; nr < 8; nr++)
                acc[nr] = __builtin_amdgcn_mfma_f32_16x16x32_bf16(bf[ks][nr], a[ks], acc[nr], 0, 0, 0);

        int row = t * 16 + (lane & 15);
        size_t rb = (size_t)row * DIM;
#pragma unroll
        for (int nr = 0; nr < 8; nr++) {
            ushort4 u;
            u.x = f2b(acc[nr][0] + bv[nr].x);
            u.y = f2b(acc[nr][1] + bv[nr].y);
            u.z = f2b(acc[nr][2] + bv[nr].z);
            u.w = f2b(acc[nr][3] + bv[nr].w);
            *(ushort4*)(C + rb + nr * 16 + colb) = u;
        }
    }
}

// ---------------- aggregation ----------------
// 2 nodes per wave: half h handles node blockIdx.x*8 + wave*2 + h with its
// 32 lanes (4 dims/lane, uint2 gathers). No cross-half merge. 4-edge unroll,
// native f32x2 math, no-max softmax via exp2 (att has log2e folded).
// Shuffle reduce offsets 16..1 stay inside each half -> divergence-safe.
#define EDGE_P(K)                                                        \
    f32x2 v01_##K = cvt2(e##K.x), v23_##K = cvt2(e##K.y);                \
    float p##K;                                                          \
    {                                                                    \
        f32x2 t01 = v01_##K + x01;                                       \
        f32x2 t23 = v23_##K + x23;                                       \
        f32x2 pp = a6_01 * t01 + a4_01 * abs2(t01);                      \
        pp += a6_23 * t23;                                               \
        pp += a4_23 * abs2(t23);                                         \
        p##K = pp.x + pp.y;                                              \
    }

__global__ __launch_bounds__(256, 8) void k_aggr(
    const unsigned short* __restrict__ XLb, const unsigned short* __restrict__ XRb,
    const unsigned short* __restrict__ RESb, const float* __restrict__ att,
    const float* __restrict__ bias, const int* __restrict__ rowptr,
    const int* __restrict__ srt, float* __restrict__ outF,
    unsigned short* __restrict__ fragOut, int writeFrag, int n)
{
    int wave = threadIdx.x >> 6;
    int lane = threadIdx.x & 63;
    int half = lane >> 5, sl = lane & 31;
    int node = blockIdx.x * 8 + wave * 2 + half;
    bool valid = node < n;
    int nclamp = valid ? node : (n - 1);
    int d0 = sl << 2;

    const float S6 = 0.6f * 1.44269504089f;   // log2(e) folded
    const float S4 = 0.4f * 1.44269504089f;
    float4 af = *(const float4*)(att + d0);
    f32x2 a6_01 = {S6 * af.x, S6 * af.y}, a6_23 = {S6 * af.z, S6 * af.w};
    f32x2 a4_01 = {S4 * af.x, S4 * af.y}, a4_23 = {S4 * af.z, S4 * af.w};

    uint2 xru = *(const uint2*)(XRb + (size_t)nclamp * DIM + d0);
    f32x2 x01 = cvt2(xru.x), x23 = cvt2(xru.y);

    int beg = rowptr[nclamp], end = valid ? rowptr[nclamp + 1] : beg;

    const uint2* R = (const uint2*)XLb;   // row i slice at R[i*32 + sl]

    f32x2 acc01 = {0.f, 0.f}, acc23 = {0.f, 0.f};
    float den = 0.f;

    for (int j = beg; j < end; j += 4) {
        int j1 = (j + 1 < end) ? j + 1 : j;
        int j2 = (j + 2 < end) ? j + 2 : j;
        int j3 = (j + 3 < end) ? j + 3 : j;
        int s0 = srt[j], s1 = srt[j1], s2 = srt[j2], s3 = srt[j3];
        uint2 e0 = R[(size_t)s0 * 32 + sl];
        uint2 e1 = R[(size_t)s1 * 32 + sl];
        uint2 e2 = R[(size_t)s2 * 32 + sl];
        uint2 e3 = R[(size_t)s3 * 32 + sl];
        EDGE_P(0) EDGE_P(1) EDGE_P(2) EDGE_P(3)
#pragma unroll
        for (int off = 16; off >= 1; off >>= 1) {
            p0 += __shfl_xor(p0, off);
            p1 += __shfl_xor(p1, off);
            p2 += __shfl_xor(p2, off);
            p3 += __shfl_xor(p3, off);
        }
        float w0 = __builtin_exp2f(fminf(p0, 120.f));
        float w1 = (j + 1 < end) ? __builtin_exp2f(fminf(p1, 120.f)) : 0.f;
        float w2 = (j + 2 < end) ? __builtin_exp2f(fminf(p2, 120.f)) : 0.f;
        float w3 = (j + 3 < end) ? __builtin_exp2f(fminf(p3, 120.f)) : 0.f;
        den += (w0 + w1) + (w2 + w3);
        acc01 += w0 * v01_0 + w1 * v01_1;
        acc23 += w0 * v23_0 + w1 * v23_1;
        acc01 += w2 * v01_2 + w3 * v01_3;
        acc23 += w2 * v23_2 + w3 * v23_3;
    }

    if (!valid) return;

    float inv = 1.f / (den + 1e-16f);
    uint2 ru = *(const uint2*)(RESb + (size_t)node * DIM + d0);
    f32x2 r01 = cvt2(ru.x), r23 = cvt2(ru.y);
    float4 b4 = *(const float4*)(bias + d0);
    float4 o;
    o.x = fmaxf(acc01.x * inv + b4.x + r01.x, 0.f);
    o.y = fmaxf(acc01.y * inv + b4.y + r01.y, 0.f);
    o.z = fmaxf(acc23.x * inv + b4.z + r23.x, 0.f);
    o.w = fmaxf(acc23.y * inv + b4.w + r23.y, 0.f);

    if (writeFrag) {
        int tile = node >> 4;
        int ks = sl >> 3;
        int li = (node & 15) + (((sl >> 1) & 3) << 4);
        int j0 = (sl & 1) << 2;
        ushort4 u;
        u.x = f2b(o.x); u.y = f2b(o.y); u.z = f2b(o.z); u.w = f2b(o.w);
        *(ushort4*)(fragOut + ((size_t)((tile * 4 + ks) * 64 + li) << 3) + j0) = u;
    } else {
        *(float4*)(outF + (size_t)node * DIM + d0) = o;
    }
}

extern "C" void kernel_launch(void* const* d_in, const int* in_sizes, int n_in,
                              void* d_out, int out_size, void* d_ws, size_t ws_size,
                              hipStream_t stream) {
    const float* x    = (const float*)d_in[0];
    const int*   ei   = (const int*)d_in[1];
    const float* Wl   = (const float*)d_in[2];
    const float* bl   = (const float*)d_in[3];
    const float* Wr   = (const float*)d_in[4];
    const float* br   = (const float*)d_in[5];
    const float* att  = (const float*)d_in[6];
    const float* bias = (const float*)d_in[7];
    const float* Wres = (const float*)d_in[8];
    const float* bres = (const float*)d_in[9];

    int n = in_sizes[0] / DIM;
    int E = in_sizes[1] / 2;
    int ntiles = (n + 15) >> 4;
    const int* srcIdx = ei;
    const int* dstIdx = ei + E;

    // workspace layout
    unsigned short* xlb   = (unsigned short*)d_ws;
    unsigned short* xrb   = xlb + (size_t)n * DIM;
    unsigned short* resb  = xrb + (size_t)n * DIM;
    unsigned short* hfrag = resb + (size_t)n * DIM;
    unsigned short* wfrag = hfrag + (size_t)ntiles * 16 * DIM;
    int* rowptr = (int*)(wfrag + 2 * 3 * DIM * DIM);
    int* tmpc   = rowptr + (n + 1);
    int* srt    = tmpc + n;                 // E+n used, +8 pad
    int* bsum   = srt + (E + n + 8);

    int nb1 = (n + 255) / 256;   // 196 <= 256

    k_pre<<<48 + ntiles + nb1, 256, 0, stream>>>(Wl, Wr, Wres, wfrag, x, hfrag,
                                                 tmpc, n, ntiles);
    k_count<<<(E + 255) / 256, 256, 0, stream>>>(dstIdx, E, tmpc);
    k_scan1<<<nb1, 256, 0, stream>>>(tmpc, n, rowptr, bsum);
    k_scan3<<<nb1, 256, 0, stream>>>(rowptr, bsum, n, tmpc, nb1);
    k_scatter<<<(E + n + 255) / 256, 256, 0, stream>>>(srcIdx, dstIdx, E, n, tmpc, srt);

    int gx = (ntiles + 4 * TPW - 1) / (4 * TPW);
    for (int l = 0; l < 2; l++) {
        dim3 g(gx, 3);
        k_gemm<<<g, 256, 0, stream>>>(hfrag, wfrag + (size_t)l * 3 * 4 * 8 * 64 * 8,
                                      bl + (size_t)l * DIM, br + (size_t)l * DIM, bres,
                                      xlb, xrb, resb, ntiles);
        k_aggr<<<(n + 7) / 8, 256, 0, stream>>>(xlb, xrb, resb, att + (size_t)l * DIM,
                                                bias + (size_t)l * DIM, rowptr, srt,
                                                (float*)d_out, hfrag, (l == 0) ? 1 : 0, n);
    }
}